// Round 10
// baseline (3671.410 us; speedup 1.0000x reference)
//
#include <hip/hip_runtime.h>
#include <hip/hip_bf16.h>
#include <stdint.h>

typedef __attribute__((ext_vector_type(8))) short short8;
typedef __attribute__((ext_vector_type(4))) short short4v;
typedef __attribute__((ext_vector_type(4))) float f32x4;
typedef __attribute__((ext_vector_type(4))) int int4v;

#define T_STEPS 512
#define BATCH 64
#define HDIM 1024
#define MROWS (T_STEPS * BATCH)  // 32768

__device__ __forceinline__ unsigned short f2bf(float f) {
  unsigned int u = __float_as_uint(f);
  u += 0x7FFFu + ((u >> 16) & 1u);  // RNE
  return (unsigned short)(u >> 16);
}

// ---------------- transpose + convert: dst[n][k] = bf16(src[k][n]), 1024x1024
__global__ __launch_bounds__(256) void transpose_cvt(const float* __restrict__ src,
                                                     unsigned short* __restrict__ dst) {
  __shared__ unsigned short tile[32][36];
  int b = blockIdx.x;
  int tr = b >> 5, tc = b & 31;
  int t = threadIdx.x;
  int i = t >> 3, j4 = (t & 7) << 2;
  const float4 v = *(const float4*)(src + (size_t)(tr * 32 + i) * 1024 + tc * 32 + j4);
  tile[i][j4 + 0] = f2bf(v.x);
  tile[i][j4 + 1] = f2bf(v.y);
  tile[i][j4 + 2] = f2bf(v.z);
  tile[i][j4 + 3] = f2bf(v.w);
  __syncthreads();
  int c = t >> 3, r4 = (t & 7) << 2;
  short4v o;
  o[0] = (short)tile[r4 + 0][c];
  o[1] = (short)tile[r4 + 1][c];
  o[2] = (short)tile[r4 + 2][c];
  o[3] = (short)tile[r4 + 3][c];
  *(short4v*)(dst + (size_t)(tc * 32 + c) * 1024 + tr * 32 + r4) = o;
}

// ---------------- device-coherent (sc0 sc1) primitives — proven transport path
__device__ __forceinline__ void coh_store_dword(int* p, int v) {
  asm volatile("global_store_dword %0, %1, off sc0 sc1" ::"v"(p), "v"(v) : "memory");
}
__device__ __forceinline__ void coh_load_x4(int4v* dst, const int* p) {
  asm volatile("global_load_dwordx4 %0, %1, off sc0 sc1" : "=&v"(*dst) : "v"(p) : "memory");
}

// =================================================================
// Fused persistent scan: inline xW GEMM (W_xh^T resident in VGPRs — R9's bug
// was using W_hh here) + R8-D-proven chunked tagged h-exchange (sc0 sc1).
// 64 WGs x 4 waves; WG (bg=wg>>4, cg=wg&15) owns rows [16bg,+16) x cols
// [64cg,+64). Wave w: K-slice [256w,+256).
// Per step: (1) inputs[s] row-tile -> bf16 A-frags, 32 MFMAs vs xfrag (W_xh);
// (2) chunked tagged poll of h_{s-1}, 32 MFMAs vs wfrag (W_hh), same acc;
// (3) one-barrier LDS reduce across waves; (4) tanh(+bias), write out +
// tagged h. No separate GEMM, no out[] reads. Spins guard-capped: no hangs.
// =================================================================
__global__ __launch_bounds__(256, 1) void rnn_fused(const unsigned short* __restrict__ whhT,
                                                    const unsigned short* __restrict__ wxhT,
                                                    const float* __restrict__ inp,
                                                    const float* __restrict__ bh,
                                                    float* __restrict__ out,
                                                    int* __restrict__ hb2) {
  int wg = blockIdx.x;
  int bg = wg >> 4;   // 0..3   rows [16bg, +16)
  int cg = wg & 15;   // 0..15  cols [64cg, +64)
  int t = threadIdx.x, lane = t & 63, wave = t >> 6;
  int l15 = lane & 15, l4 = lane >> 4;

  __shared__ __align__(16) float red[2][4][64][4][4];  // [parity][wave][lane][coltile][4]

  // Weight fragments resident in VGPRs for all 512 steps (128 VGPRs each set):
  // cols [64cg+16c+l15], k = 256*wave + 32m + 8*l4 .. +8
  short8 wfrag[4][8];  // W_hh^T — recurrent term
  short8 xfrag[4][8];  // W_xh^T — input-projection term
#pragma unroll
  for (int c = 0; c < 4; ++c)
#pragma unroll
    for (int m = 0; m < 8; ++m) {
      size_t off = (size_t)(64 * cg + 16 * c + l15) * 1024 + 256 * wave + 32 * m + 8 * l4;
      wfrag[c][m] = *(const short8*)(whhT + off);
      xfrag[c][m] = *(const short8*)(wxhT + off);
    }

  int colw = 64 * cg + 16 * wave + l15;  // this thread's epilogue column
  float bias = bh[colw];

  for (int s = 0; s < T_STEPS; ++s) {
    f32x4 acc[4];
#pragma unroll
    for (int c = 0; c < 4; ++c) acc[c] = (f32x4){0.f, 0.f, 0.f, 0.f};

    // ---- (1) inline xW: A-frags from inputs[s] (rows 16bg+l15, K 256w), vs W_xh
    {
      const float* ibase = inp + ((size_t)s * BATCH + 16 * bg + l15) * HDIM + 256 * wave + 8 * l4;
#pragma unroll
      for (int m = 0; m < 8; ++m) {
        float4 u0 = *(const float4*)(ibase + 32 * m);
        float4 u1 = *(const float4*)(ibase + 32 * m + 4);
        short8 af;
        af[0] = (short)f2bf(u0.x); af[1] = (short)f2bf(u0.y);
        af[2] = (short)f2bf(u0.z); af[3] = (short)f2bf(u0.w);
        af[4] = (short)f2bf(u1.x); af[5] = (short)f2bf(u1.y);
        af[6] = (short)f2bf(u1.z); af[7] = (short)f2bf(u1.w);
#pragma unroll
        for (int c = 0; c < 4; ++c)
          acc[c] = __builtin_amdgcn_mfma_f32_16x16x32_bf16(af, xfrag[c][m], acc[c], 0, 0, 0);
      }
    }

    // ---- (2) recurrent part: chunked tagged consume (R8-D proven), vs W_hh
    if (s > 0) {
      const unsigned tagv = (unsigned)s;  // tag of h_{s-1}
      const int* base = hb2 + (((s - 1) & 1) << 16) + (16 * bg + l15) * 1024 + 256 * wave;
#pragma unroll
      for (int jj = 0; jj < 4; ++jj) {  // one producer-WG's K-64 chunk each
        const int* fb = base + 64 * jj + 8 * l4;
        int4v c0, c1, c2, c3;
        int guard = 0;
        for (;;) {
          coh_load_x4(&c0, fb);
          coh_load_x4(&c1, fb + 4);
          coh_load_x4(&c2, fb + 32);
          coh_load_x4(&c3, fb + 36);
          asm volatile("s_waitcnt vmcnt(0)" ::: "memory");
          __builtin_amdgcn_sched_barrier(0);
          unsigned bad = 0;
#pragma unroll
          for (int e = 0; e < 4; ++e)
            bad |= (((unsigned)c0[e] >> 16) ^ tagv) | (((unsigned)c1[e] >> 16) ^ tagv) |
                   (((unsigned)c2[e] >> 16) ^ tagv) | (((unsigned)c3[e] >> 16) ^ tagv);
          if (__all(bad == 0)) break;
          if (++guard > 16384) break;  // fail-safe: wrong result, never a hang
        }
        int4v p0, p1;
        p0[0] = (c0[0] & 0xffff) | (c0[1] << 16);
        p0[1] = (c0[2] & 0xffff) | (c0[3] << 16);
        p0[2] = (c1[0] & 0xffff) | (c1[1] << 16);
        p0[3] = (c1[2] & 0xffff) | (c1[3] << 16);
        p1[0] = (c2[0] & 0xffff) | (c2[1] << 16);
        p1[1] = (c2[2] & 0xffff) | (c2[3] << 16);
        p1[2] = (c3[0] & 0xffff) | (c3[1] << 16);
        p1[3] = (c3[2] & 0xffff) | (c3[3] << 16);
#pragma unroll
        for (int c = 0; c < 4; ++c) {
          acc[c] = __builtin_amdgcn_mfma_f32_16x16x32_bf16(*(short8*)&p0, wfrag[c][2 * jj],
                                                           acc[c], 0, 0, 0);
          acc[c] = __builtin_amdgcn_mfma_f32_16x16x32_bf16(*(short8*)&p1, wfrag[c][2 * jj + 1],
                                                           acc[c], 0, 0, 0);
        }
      }
    }

    // ---- (3) cross-wave reduce (single barrier, parity-buffered)
    int p = s & 1;
#pragma unroll
    for (int c = 0; c < 4; ++c) *(f32x4*)&red[p][wave][lane][c][0] = acc[c];
    __syncthreads();
    f32x4 hsum;
#pragma unroll
    for (int r = 0; r < 4; ++r)
      hsum[r] = red[p][0][lane][wave][r] + red[p][1][lane][wave][r] +
                red[p][2][lane][wave][r] + red[p][3][lane][wave][r];

    // ---- (4) epilogue
#pragma unroll
    for (int r = 0; r < 4; ++r) {
      int row = bg * 16 + l4 * 4 + r;
      size_t oidx = ((size_t)s * BATCH + row) * HDIM + colw;
      float hv = tanhf(hsum[r] + bias);
      out[oidx] = hv;
      if (s != T_STEPS - 1)
        coh_store_dword(hb2 + ((s & 1) << 16) + row * 1024 + colw,
                        (int)(((unsigned)(s + 1) << 16) | (unsigned)f2bf(hv)));
      else
        out[(size_t)MROWS * HDIM + (size_t)row * HDIM + colw] = hv;  // last_state
    }
  }
}

extern "C" void kernel_launch(void* const* d_in, const int* in_sizes, int n_in,
                              void* d_out, int out_size, void* d_ws, size_t ws_size,
                              hipStream_t stream) {
  const float* inp = (const float*)d_in[0];   // [512,64,1024] fp32
  const float* wxh = (const float*)d_in[1];   // [1024,1024]
  const float* whh = (const float*)d_in[2];   // [1024,1024]
  const float* bh  = (const float*)d_in[3];   // [1024]
  float* out = (float*)d_out;

  char* ws = (char*)d_ws;
  unsigned short* whhT = (unsigned short*)(ws);            // 2 MB
  unsigned short* wxhT = (unsigned short*)(ws + (2u << 20));  // 2 MB
  int* hb2 = (int*)(ws + (4u << 20));                      // 512 KB tagged ping-pong

  // clear stale tags each launch (tag 0 never matches; deterministic under replay)
  hipMemsetAsync(hb2, 0, 2u * BATCH * HDIM * sizeof(int), stream);
  transpose_cvt<<<1024, 256, 0, stream>>>(whh, whhT);
  transpose_cvt<<<1024, 256, 0, stream>>>(wxh, wxhT);
  rnn_fused<<<64, 256, 0, stream>>>(whhT, wxhT, inp, bh, out, hb2);
}